// Round 1
// baseline (1704.886 us; speedup 1.0000x reference)
//
#include <hip/hip_runtime.h>
#include <hip/hip_bf16.h>
#include <cstdint>
#include <cstddef>

#define N_TOKENS  4096
#define DIM       2048
#define N_EXPERTS 32
#define TOPK      4
#define INTER     1408
#define TWO_INTER 2816
#define CAP       1024
#define T_ASSIGN  (N_TOKENS*TOPK)

typedef __attribute__((ext_vector_type(8))) short short8;
typedef __attribute__((ext_vector_type(4))) float f32x4;

// fp32 -> 2x bf16 packed into u32 (round-to-nearest via +0x8000)
__device__ __forceinline__ unsigned pack_bf16(float a, float b) {
  unsigned ua = __builtin_bit_cast(unsigned, a);
  unsigned ub = __builtin_bit_cast(unsigned, b);
  ua = (ua + 0x8000u) >> 16;
  ub = (ub + 0x8000u) & 0xFFFF0000u;
  return ua | ub;
}

// LDS swizzle: rows are 128 bytes (64 bf16). XOR k-byte with row-derived 16B slot.
__device__ __forceinline__ int swz(int r) { return ((r ^ (r >> 3)) & 7) << 4; }
__device__ __forceinline__ int lds_off(int row, int kbyte) {
  return row * 128 + (kbyte ^ swz(row));
}

// ---------------- routing build ----------------
__global__ void k_build(const int* __restrict__ tmask, const float* __restrict__ w,
                        const int* __restrict__ idx, int* __restrict__ counts,
                        int* __restrict__ tok, float* __restrict__ pb) {
  int i = blockIdx.x * 256 + threadIdx.x;
  if (i >= T_ASSIGN) return;
  int t = i >> 2;
  int e = idx[i];
  if (e < 0 || e >= N_EXPERTS) return;
  if (tmask[t] == 0) return;
  int r = atomicAdd(&counts[e], 1);
  if (r < CAP) {
    tok[e * CAP + r] = t;
    pb[e * CAP + r] = w[i];
  }
}

// ---------------- GEMM1: h = gather(x) @ gup[e], fused GEGLU*prob -> act (bf16) ----------------
__global__ __launch_bounds__(256) void k_gemm1(
    const float* __restrict__ x, const float* __restrict__ gup,
    const int* __restrict__ counts, const int* __restrict__ tok,
    const float* __restrict__ pb, __hip_bfloat16* __restrict__ act)
{
  const int MT = CAP / 128;        // 8
  const int NT = TWO_INTER / 128;  // 22
  int bid = blockIdx.x;
  int e  = bid / (NT * MT);
  int rr = bid % (NT * MT);
  int nt = rr / MT;
  int mt = rr % MT;
  const int cnt = counts[e];
  const int m0 = mt * 128;
  if (m0 >= cnt) return;
  const int n0 = nt * 128;

  __shared__ unsigned char AsB[128 * 128];
  __shared__ unsigned char BsB[128 * 128];
  __shared__ int toks[128];

  const int tid  = threadIdx.x;
  const int lane = tid & 63;
  const int wid  = tid >> 6;
  const int wr = wid >> 1, wc = wid & 1;

  if (tid < 128) toks[tid] = tok[e * CAP + m0 + tid];
  __syncthreads();

  // A staging: p=0..7 handles row m=(tid>>4)+16p, float-col base (tid&15)*4
  const float* aptr[8];
  {
    int mrow = tid >> 4;
    int kcb  = (tid & 15) * 4;
    #pragma unroll
    for (int p = 0; p < 8; ++p)
      aptr[p] = x + (size_t)toks[mrow + 16 * p] * DIM + kcb;
  }
  const float* gb = gup + (size_t)e * DIM * TWO_INTER + n0;

  int nb[2], kb[2];
  #pragma unroll
  for (int p = 0; p < 2; ++p) { int q = p * 256 + tid; nb[p] = q & 31; kb[p] = q >> 5; }

  f32x4 acc[4][4];
  #pragma unroll
  for (int i = 0; i < 4; ++i)
    #pragma unroll
    for (int j = 0; j < 4; ++j) acc[i][j] = (f32x4){0.f, 0.f, 0.f, 0.f};

  const int aw_kbyte = (tid & 15) * 8;
  const int aw_rowb  = tid >> 4;

  for (int kt = 0; kt < DIM / 64; ++kt) {
    int k0 = kt * 64;
    float4 av[8];
    #pragma unroll
    for (int p = 0; p < 8; ++p) av[p] = *(const float4*)(aptr[p] + k0);
    float4 bv[2][4];
    #pragma unroll
    for (int p = 0; p < 2; ++p) {
      const float* bp = gb + (size_t)(k0 + kb[p] * 4) * TWO_INTER + nb[p] * 4;
      #pragma unroll
      for (int j = 0; j < 4; ++j) bv[p][j] = *(const float4*)(bp + (size_t)j * TWO_INTER);
    }
    __syncthreads();  // previous iteration's LDS reads done
    #pragma unroll
    for (int p = 0; p < 8; ++p) {
      int m = aw_rowb + 16 * p;
      unsigned lo = pack_bf16(av[p].x, av[p].y);
      unsigned hi = pack_bf16(av[p].z, av[p].w);
      *(uint2*)(AsB + lds_off(m, aw_kbyte)) = make_uint2(lo, hi);
    }
    #pragma unroll
    for (int p = 0; p < 2; ++p) {
      #pragma unroll
      for (int c = 0; c < 4; ++c) {
        int n = nb[p] * 4 + c;
        unsigned lo = pack_bf16(((const float*)&bv[p][0])[c], ((const float*)&bv[p][1])[c]);
        unsigned hi = pack_bf16(((const float*)&bv[p][2])[c], ((const float*)&bv[p][3])[c]);
        *(uint2*)(BsB + lds_off(n, kb[p] * 8)) = make_uint2(lo, hi);
      }
    }
    __syncthreads();
    #pragma unroll
    for (int ks = 0; ks < 2; ++ks) {
      short8 af[4], bf[4];
      int kbyte = ks * 64 + (lane >> 4) * 16;
      #pragma unroll
      for (int mi = 0; mi < 4; ++mi) {
        int row = wr * 64 + mi * 16 + (lane & 15);
        af[mi] = *(const short8*)(AsB + lds_off(row, kbyte));
      }
      #pragma unroll
      for (int ni = 0; ni < 4; ++ni) {
        int rown = wc * 64 + ni * 16 + (lane & 15);
        bf[ni] = *(const short8*)(BsB + lds_off(rown, kbyte));
      }
      #pragma unroll
      for (int mi = 0; mi < 4; ++mi)
        #pragma unroll
        for (int ni = 0; ni < 4; ++ni)
          acc[mi][ni] = __builtin_amdgcn_mfma_f32_16x16x32_bf16(af[mi], bf[ni], acc[mi][ni], 0, 0, 0);
    }
  }

  // epilogue: pair even/odd columns (gate/up interleaved), GEGLU * prob -> bf16 act
  const int colp = lane & 15;
  const int rgrp = lane >> 4;
  #pragma unroll
  for (int mi = 0; mi < 4; ++mi) {
    #pragma unroll
    for (int j = 0; j < 4; ++j) {
      int rowl = wr * 64 + mi * 16 + rgrp * 4 + j;
      float prob = pb[e * CAP + m0 + rowl];
      size_t arow = (size_t)(e * CAP + m0 + rowl) * INTER;
      #pragma unroll
      for (int ni = 0; ni < 4; ++ni) {
        float v = acc[mi][ni][j];
        float other = __shfl_xor(v, 1, 64);
        if ((lane & 1) == 0) {
          float gate = fminf(v, 7.0f);
          float up   = fminf(fmaxf(other, -7.0f), 7.0f);
          float glu  = gate / (1.0f + __expf(-1.702f * gate));
          float a    = glu * (up + 1.0f) * prob;
          int nh = n0 + wc * 64 + ni * 16 + colp;  // even column
          act[arow + (nh >> 1)] = __float2bfloat16(a);
        }
      }
    }
  }
}

// ---------------- GEMM2: y = act @ down[e], atomicAdd into out ----------------
__global__ __launch_bounds__(256) void k_gemm2(
    const __hip_bfloat16* __restrict__ act, const float* __restrict__ down,
    const int* __restrict__ counts, const int* __restrict__ tok,
    float* __restrict__ out)
{
  const int MT = CAP / 128;  // 8
  const int NT = DIM / 128;  // 16
  int bid = blockIdx.x;
  int e  = bid / (NT * MT);
  int rr = bid % (NT * MT);
  int nt = rr / MT;
  int mt = rr % MT;
  const int cnt = counts[e];
  const int m0 = mt * 128;
  if (m0 >= cnt) return;
  const int n0 = nt * 128;

  __shared__ unsigned char AsB[128 * 128];
  __shared__ unsigned char BsB[128 * 128];

  const int tid  = threadIdx.x;
  const int lane = tid & 63;
  const int wid  = tid >> 6;
  const int wr = wid >> 1, wc = wid & 1;

  const __hip_bfloat16* ab = act + (size_t)(e * CAP + m0) * INTER;
  const float* gb = down + (size_t)e * INTER * DIM + n0;

  int nb[2], kb[2];
  #pragma unroll
  for (int p = 0; p < 2; ++p) { int q = p * 256 + tid; nb[p] = q & 31; kb[p] = q >> 5; }
  int am[4], ak[4];
  #pragma unroll
  for (int p = 0; p < 4; ++p) { int q = p * 256 + tid; am[p] = q >> 3; ak[p] = q & 7; }

  f32x4 acc[4][4];
  #pragma unroll
  for (int i = 0; i < 4; ++i)
    #pragma unroll
    for (int j = 0; j < 4; ++j) acc[i][j] = (f32x4){0.f, 0.f, 0.f, 0.f};

  const int KT = INTER / 64;  // 22
  for (int kt = 0; kt < KT; ++kt) {
    int k0 = kt * 64;
    uint4 avv[4];
    #pragma unroll
    for (int p = 0; p < 4; ++p)
      avv[p] = *(const uint4*)(ab + (size_t)am[p] * INTER + k0 + ak[p] * 8);
    float4 bv[2][4];
    #pragma unroll
    for (int p = 0; p < 2; ++p) {
      const float* bp = gb + (size_t)(k0 + kb[p] * 4) * DIM + nb[p] * 4;
      #pragma unroll
      for (int j = 0; j < 4; ++j) bv[p][j] = *(const float4*)(bp + (size_t)j * DIM);
    }
    __syncthreads();
    #pragma unroll
    for (int p = 0; p < 4; ++p)
      *(uint4*)(AsB + lds_off(am[p], ak[p] * 16)) = avv[p];
    #pragma unroll
    for (int p = 0; p < 2; ++p) {
      #pragma unroll
      for (int c = 0; c < 4; ++c) {
        int n = nb[p] * 4 + c;
        unsigned lo = pack_bf16(((const float*)&bv[p][0])[c], ((const float*)&bv[p][1])[c]);
        unsigned hi = pack_bf16(((const float*)&bv[p][2])[c], ((const float*)&bv[p][3])[c]);
        *(uint2*)(BsB + lds_off(n, kb[p] * 8)) = make_uint2(lo, hi);
      }
    }
    __syncthreads();
    #pragma unroll
    for (int ks = 0; ks < 2; ++ks) {
      short8 af[4], bf[4];
      int kbyte = ks * 64 + (lane >> 4) * 16;
      #pragma unroll
      for (int mi = 0; mi < 4; ++mi) {
        int row = wr * 64 + mi * 16 + (lane & 15);
        af[mi] = *(const short8*)(AsB + lds_off(row, kbyte));
      }
      #pragma unroll
      for (int ni = 0; ni < 4; ++ni) {
        int rown = wc * 64 + ni * 16 + (lane & 15);
        bf[ni] = *(const short8*)(BsB + lds_off(rown, kbyte));
      }
      #pragma unroll
      for (int mi = 0; mi < 4; ++mi)
        #pragma unroll
        for (int ni = 0; ni < 4; ++ni)
          acc[mi][ni] = __builtin_amdgcn_mfma_f32_16x16x32_bf16(af[mi], bf[ni], acc[mi][ni], 0, 0, 0);
    }
  }

  const int colp = lane & 15;
  const int rgrp = lane >> 4;
  #pragma unroll
  for (int mi = 0; mi < 4; ++mi) {
    #pragma unroll
    for (int j = 0; j < 4; ++j) {
      int rowl = wr * 64 + mi * 16 + rgrp * 4 + j;
      int t = tok[e * CAP + m0 + rowl];
      float* orow = out + (size_t)t * DIM + n0;
      #pragma unroll
      for (int ni = 0; ni < 4; ++ni)
        atomicAdd(orow + wc * 64 + ni * 16 + colp, acc[mi][ni][j]);
    }
  }
}

extern "C" void kernel_launch(void* const* d_in, const int* in_sizes, int n_in,
                              void* d_out, int out_size, void* d_ws, size_t ws_size,
                              hipStream_t stream) {
  const float* x     = (const float*)d_in[0];
  const int*   tmask = (const int*)d_in[1];
  const float* w     = (const float*)d_in[2];
  const int*   idx   = (const int*)d_in[3];
  const float* gup   = (const float*)d_in[4];
  const float* down  = (const float*)d_in[5];
  float* out = (float*)d_out;

  char* ws = (char*)d_ws;
  int*   counts = (int*)ws;                          // 128 B used, pad to 256
  int*   tok    = (int*)(ws + 256);                  // 32*1024*4 = 131072 B
  float* pb     = (float*)(ws + 256 + 131072);       // 131072 B
  __hip_bfloat16* act = (__hip_bfloat16*)(ws + 256 + 262144);  // 32*1024*1408*2 B

  hipMemsetAsync(ws, 0, 256 + 262144, stream);
  k_build<<<(T_ASSIGN + 255) / 256, 256, 0, stream>>>(tmask, w, idx, counts, tok, pb);
  hipMemsetAsync(d_out, 0, (size_t)N_TOKENS * DIM * sizeof(float), stream);

  k_gemm1<<<N_EXPERTS * (TWO_INTER / 128) * (CAP / 128), 256, 0, stream>>>(
      x, gup, counts, tok, pb, act);
  k_gemm2<<<N_EXPERTS * (DIM / 128) * (CAP / 128), 256, 0, stream>>>(
      act, down, counts, tok, out);
}

// Round 2
// 1567.585 us; speedup vs baseline: 1.0876x; 1.0876x over previous
//
#include <hip/hip_runtime.h>
#include <hip/hip_bf16.h>
#include <cstdint>
#include <cstddef>

#define N_TOKENS  4096
#define DIM       2048
#define N_EXPERTS 32
#define TOPK      4
#define INTER     1408
#define TWO_INTER 2816
#define CAP       1024
#define T_ASSIGN  (N_TOKENS*TOPK)

typedef __attribute__((ext_vector_type(8))) short short8;
typedef __attribute__((ext_vector_type(4))) float f32x4;

__device__ __forceinline__ unsigned pack_bf16(float a, float b) {
  unsigned ua = __builtin_bit_cast(unsigned, a);
  unsigned ub = __builtin_bit_cast(unsigned, b);
  ua = (ua + 0x8000u) >> 16;
  ub = (ub + 0x8000u) & 0xFFFF0000u;
  return ua | ub;
}
__device__ __forceinline__ unsigned short bf16_1(float a) {
  return (unsigned short)((__builtin_bit_cast(unsigned, a) + 0x8000u) >> 16);
}

// async global(per-lane addr) -> LDS(linear, base+lane*16)
__device__ __forceinline__ void gl_lds16(const void* g, void* l) {
  __builtin_amdgcn_global_load_lds(
      (const __attribute__((address_space(1))) unsigned int*)g,
      (__attribute__((address_space(3))) unsigned int*)l, 16, 0, 0);
}

// ---------------- routing build ----------------
__global__ void k_build(const int* __restrict__ tmask, const float* __restrict__ w,
                        const int* __restrict__ idx, int* __restrict__ counts,
                        int* __restrict__ tok, float* __restrict__ pb) {
  int i = blockIdx.x * 256 + threadIdx.x;
  if (i >= T_ASSIGN) return;
  int t = i >> 2;
  int e = idx[i];
  if (e < 0 || e >= N_EXPERTS) return;
  if (tmask[t] == 0) return;
  int r = atomicAdd(&counts[e], 1);
  if (r < CAP) {
    tok[e * CAP + r] = t;
    pb[e * CAP + r] = w[i];
  }
}

// ---------------- fp32 -> bf16 linear convert ----------------
__global__ __launch_bounds__(256) void k_conv(const float* __restrict__ src,
                                              __hip_bfloat16* __restrict__ dst, int n4) {
  int i = blockIdx.x * 256 + threadIdx.x;
  int stride = gridDim.x * 256;
  for (; i < n4; i += stride) {
    float4 v = *(const float4*)(src + (size_t)i * 4);
    *(uint2*)(dst + (size_t)i * 4) = make_uint2(pack_bf16(v.x, v.y), pack_bf16(v.z, v.w));
  }
}

// ---------------- fp32 [E][R][C] -> bf16 [E][C][R] transpose-convert ----------------
__global__ __launch_bounds__(256) void k_tconv(const float* __restrict__ src,
                                               __hip_bfloat16* __restrict__ dst,
                                               int R, int C) {
  __shared__ unsigned short s[64][88];  // [c][r], stride 88 (176B, 16B-aligned rows)
  int nrt = R >> 6, nct = C >> 6;
  int bid = blockIdx.x;
  int e  = bid / (nrt * nct);
  int rr = bid % (nrt * nct);
  int rt = rr / nct, ct = rr % nct;
  int r0 = rt * 64, c0 = ct * 64;
  const float* sp = src + (size_t)e * R * C;
  int t = threadIdx.x;
  int lr  = t >> 4;          // 0..15
  int lc4 = (t & 15) * 4;    // 0..60
  #pragma unroll
  for (int p = 0; p < 4; ++p) {
    int r = lr + p * 16;
    float4 v = *(const float4*)(sp + (size_t)(r0 + r) * C + c0 + lc4);
    s[lc4 + 0][r] = bf16_1(v.x);
    s[lc4 + 1][r] = bf16_1(v.y);
    s[lc4 + 2][r] = bf16_1(v.z);
    s[lc4 + 3][r] = bf16_1(v.w);
  }
  __syncthreads();
  __hip_bfloat16* dp = dst + (size_t)e * C * R;
  int wc   = t >> 2;         // 0..63: column of source tile = row of dst
  int wr16 = (t & 3) * 16;   // 0,16,32,48
  uint4 o0 = *(const uint4*)&s[wc][wr16];
  uint4 o1 = *(const uint4*)&s[wc][wr16 + 8];
  __hip_bfloat16* o = dp + (size_t)(c0 + wc) * R + r0 + wr16;
  *(uint4*)o = o0;
  *(uint4*)(o + 8) = o1;
}

// ================= fast path: m97-structure grouped GEMMs =================

// GEMM1: act[e*CAP+m][h] = GEGLU( gather(xb) @ gupT[e]^T ) * prob
__global__ __launch_bounds__(256) void k_gemm1n(
    const __hip_bfloat16* __restrict__ xb, const __hip_bfloat16* __restrict__ gupT,
    const int* __restrict__ counts, const int* __restrict__ tok,
    const float* __restrict__ pb, __hip_bfloat16* __restrict__ act)
{
  const int MT = CAP / 128;        // 8
  const int NT = TWO_INTER / 128;  // 22
  const int nwg = N_EXPERTS * NT * MT;  // 5632, %8==0
  int bid = (int)((blockIdx.x & 7) * (nwg >> 3) + (blockIdx.x >> 3));
  int e  = bid / (NT * MT);
  int rr = bid % (NT * MT);
  int nt = rr / MT, mt = rr % MT;
  const int cnt = counts[e];
  const int m0 = mt * 128;
  if (m0 >= cnt) return;
  const int n0 = nt * 128;

  __shared__ __hip_bfloat16 As[128 * 64];
  __shared__ __hip_bfloat16 Bs[128 * 64];
  __shared__ int toks[128];

  const int tid = threadIdx.x, lane = tid & 63, w = tid >> 6;
  const int wr = w >> 1, wc = w & 1;
  if (tid < 128) toks[tid] = tok[e * CAP + m0 + tid];
  __syncthreads();

  const __hip_bfloat16* gT = gupT + (size_t)e * TWO_INTER * DIM;
  const __hip_bfloat16* ab[4];
  const __hip_bfloat16* bb[4];
  const int kc8 = (lane & 7) * 8;
  #pragma unroll
  for (int i = 0; i < 4; ++i) {
    int row = w * 8 + 32 * i + (lane >> 3);
    ab[i] = xb + (size_t)toks[row] * DIM + kc8;
    bb[i] = gT + (size_t)(n0 + row) * DIM + kc8;
  }

  f32x4 acc[4][4];
  #pragma unroll
  for (int i = 0; i < 4; ++i)
    #pragma unroll
    for (int j = 0; j < 4; ++j) acc[i][j] = (f32x4){0.f, 0.f, 0.f, 0.f};

  for (int kt = 0; kt < DIM / 64; ++kt) {
    const int k0 = kt * 64;
    #pragma unroll
    for (int i = 0; i < 4; ++i) {
      int loff = (w * 64 + 256 * i + lane) * 16;
      gl_lds16(ab[i] + k0, (char*)As + loff);
      gl_lds16(bb[i] + k0, (char*)Bs + loff);
    }
    __syncthreads();
    #pragma unroll
    for (int ks = 0; ks < 2; ++ks) {
      short8 af[4], bf[4];
      const int koff = ks * 64 + (lane >> 4) * 16;
      #pragma unroll
      for (int mi = 0; mi < 4; ++mi)
        af[mi] = *(const short8*)((const char*)As + (wr * 64 + mi * 16 + (lane & 15)) * 128 + koff);
      #pragma unroll
      for (int ni = 0; ni < 4; ++ni)
        bf[ni] = *(const short8*)((const char*)Bs + (wc * 64 + ni * 16 + (lane & 15)) * 128 + koff);
      #pragma unroll
      for (int mi = 0; mi < 4; ++mi)
        #pragma unroll
        for (int ni = 0; ni < 4; ++ni)
          acc[mi][ni] = __builtin_amdgcn_mfma_f32_16x16x32_bf16(af[mi], bf[ni], acc[mi][ni], 0, 0, 0);
    }
    __syncthreads();
  }

  const int colp = lane & 15;
  const int rgrp = lane >> 4;
  #pragma unroll
  for (int mi = 0; mi < 4; ++mi) {
    #pragma unroll
    for (int j = 0; j < 4; ++j) {
      int rowl = wr * 64 + mi * 16 + rgrp * 4 + j;
      float prob = pb[e * CAP + m0 + rowl];
      size_t arow = (size_t)(e * CAP + m0 + rowl) * INTER;
      #pragma unroll
      for (int ni = 0; ni < 4; ++ni) {
        float v = acc[mi][ni][j];
        float other = __shfl_xor(v, 1, 64);
        if ((lane & 1) == 0) {
          float gate = fminf(v, 7.0f);
          float up   = fminf(fmaxf(other, -7.0f), 7.0f);
          float glu  = gate / (1.0f + __expf(-1.702f * gate));
          float a    = glu * (up + 1.0f) * prob;
          int nh = n0 + wc * 64 + ni * 16 + colp;
          act[arow + (nh >> 1)] = __float2bfloat16(a);
        }
      }
    }
  }
}

// GEMM2: out[tok] += act @ downT[e]^T
__global__ __launch_bounds__(256) void k_gemm2n(
    const __hip_bfloat16* __restrict__ act, const __hip_bfloat16* __restrict__ downT,
    const int* __restrict__ counts, const int* __restrict__ tok,
    float* __restrict__ out)
{
  const int MT = CAP / 128;  // 8
  const int NT = DIM / 128;  // 16
  const int nwg = N_EXPERTS * NT * MT;  // 4096
  int bid = (int)((blockIdx.x & 7) * (nwg >> 3) + (blockIdx.x >> 3));
  int e  = bid / (NT * MT);
  int rr = bid % (NT * MT);
  int nt = rr / MT, mt = rr % MT;
  const int cnt = counts[e];
  const int m0 = mt * 128;
  if (m0 >= cnt) return;
  const int n0 = nt * 128;

  __shared__ __hip_bfloat16 As[128 * 64];
  __shared__ __hip_bfloat16 Bs[128 * 64];

  const int tid = threadIdx.x, lane = tid & 63, w = tid >> 6;
  const int wr = w >> 1, wc = w & 1;

  const __hip_bfloat16* dT = downT + (size_t)e * DIM * INTER;
  const __hip_bfloat16* ab[4];
  const __hip_bfloat16* bb[4];
  const int kc8 = (lane & 7) * 8;
  #pragma unroll
  for (int i = 0; i < 4; ++i) {
    int row = w * 8 + 32 * i + (lane >> 3);
    ab[i] = act + (size_t)(e * CAP + m0 + row) * INTER + kc8;
    bb[i] = dT + (size_t)(n0 + row) * INTER + kc8;
  }

  f32x4 acc[4][4];
  #pragma unroll
  for (int i = 0; i < 4; ++i)
    #pragma unroll
    for (int j = 0; j < 4; ++j) acc[i][j] = (f32x4){0.f, 0.f, 0.f, 0.f};

  for (int kt = 0; kt < INTER / 64; ++kt) {
    const int k0 = kt * 64;
    #pragma unroll
    for (int i = 0; i < 4; ++i) {
      int loff = (w * 64 + 256 * i + lane) * 16;
      gl_lds16(ab[i] + k0, (char*)As + loff);
      gl_lds16(bb[i] + k0, (char*)Bs + loff);
    }
    __syncthreads();
    #pragma unroll
    for (int ks = 0; ks < 2; ++ks) {
      short8 af[4], bf[4];
      const int koff = ks * 64 + (lane >> 4) * 16;
      #pragma unroll
      for (int mi = 0; mi < 4; ++mi)
        af[mi] = *(const short8*)((const char*)As + (wr * 64 + mi * 16 + (lane & 15)) * 128 + koff);
      #pragma unroll
      for (int ni = 0; ni < 4; ++ni)
        bf[ni] = *(const short8*)((const char*)Bs + (wc * 64 + ni * 16 + (lane & 15)) * 128 + koff);
      #pragma unroll
      for (int mi = 0; mi < 4; ++mi)
        #pragma unroll
        for (int ni = 0; ni < 4; ++ni)
          acc[mi][ni] = __builtin_amdgcn_mfma_f32_16x16x32_bf16(af[mi], bf[ni], acc[mi][ni], 0, 0, 0);
    }
    __syncthreads();
  }

  const int colp = lane & 15;
  const int rgrp = lane >> 4;
  __shared__ int toks2[128];
  if (tid < 128) toks2[tid] = tok[e * CAP + m0 + tid];
  __syncthreads();
  #pragma unroll
  for (int mi = 0; mi < 4; ++mi) {
    #pragma unroll
    for (int j = 0; j < 4; ++j) {
      int rowl = wr * 64 + mi * 16 + rgrp * 4 + j;
      int t = toks2[rowl];
      float* orow = out + (size_t)t * DIM + n0;
      #pragma unroll
      for (int ni = 0; ni < 4; ++ni)
        atomicAdd(orow + wc * 64 + ni * 16 + colp, acc[mi][ni][j]);
    }
  }
}

// ================= fallback path (round-1, known-good) =================

__device__ __forceinline__ int swz(int r) { return ((r ^ (r >> 3)) & 7) << 4; }
__device__ __forceinline__ int lds_off(int row, int kbyte) {
  return row * 128 + (kbyte ^ swz(row));
}

__global__ __launch_bounds__(256) void k_gemm1(
    const float* __restrict__ x, const float* __restrict__ gup,
    const int* __restrict__ counts, const int* __restrict__ tok,
    const float* __restrict__ pb, __hip_bfloat16* __restrict__ act)
{
  const int MT = CAP / 128;
  const int NT = TWO_INTER / 128;
  int bid = blockIdx.x;
  int e  = bid / (NT * MT);
  int rr = bid % (NT * MT);
  int nt = rr / MT;
  int mt = rr % MT;
  const int cnt = counts[e];
  const int m0 = mt * 128;
  if (m0 >= cnt) return;
  const int n0 = nt * 128;

  __shared__ unsigned char AsB[128 * 128];
  __shared__ unsigned char BsB[128 * 128];
  __shared__ int toks[128];

  const int tid  = threadIdx.x;
  const int lane = tid & 63;
  const int wid  = tid >> 6;
  const int wr = wid >> 1, wc = wid & 1;

  if (tid < 128) toks[tid] = tok[e * CAP + m0 + tid];
  __syncthreads();

  const float* aptr[8];
  {
    int mrow = tid >> 4;
    int kcb  = (tid & 15) * 4;
    #pragma unroll
    for (int p = 0; p < 8; ++p)
      aptr[p] = x + (size_t)toks[mrow + 16 * p] * DIM + kcb;
  }
  const float* gb = gup + (size_t)e * DIM * TWO_INTER + n0;

  int nb[2], kb[2];
  #pragma unroll
  for (int p = 0; p < 2; ++p) { int q = p * 256 + tid; nb[p] = q & 31; kb[p] = q >> 5; }

  f32x4 acc[4][4];
  #pragma unroll
  for (int i = 0; i < 4; ++i)
    #pragma unroll
    for (int j = 0; j < 4; ++j) acc[i][j] = (f32x4){0.f, 0.f, 0.f, 0.f};

  const int aw_kbyte = (tid & 15) * 8;
  const int aw_rowb  = tid >> 4;

  for (int kt = 0; kt < DIM / 64; ++kt) {
    int k0 = kt * 64;
    float4 av[8];
    #pragma unroll
    for (int p = 0; p < 8; ++p) av[p] = *(const float4*)(aptr[p] + k0);
    float4 bv[2][4];
    #pragma unroll
    for (int p = 0; p < 2; ++p) {
      const float* bp = gb + (size_t)(k0 + kb[p] * 4) * TWO_INTER + nb[p] * 4;
      #pragma unroll
      for (int j = 0; j < 4; ++j) bv[p][j] = *(const float4*)(bp + (size_t)j * TWO_INTER);
    }
    __syncthreads();
    #pragma unroll
    for (int p = 0; p < 8; ++p) {
      int m = aw_rowb + 16 * p;
      *(uint2*)(AsB + lds_off(m, aw_kbyte)) =
          make_uint2(pack_bf16(av[p].x, av[p].y), pack_bf16(av[p].z, av[p].w));
    }
    #pragma unroll
    for (int p = 0; p < 2; ++p) {
      #pragma unroll
      for (int c = 0; c < 4; ++c) {
        int n = nb[p] * 4 + c;
        *(uint2*)(BsB + lds_off(n, kb[p] * 8)) =
            make_uint2(pack_bf16(((const float*)&bv[p][0])[c], ((const float*)&bv[p][1])[c]),
                       pack_bf16(((const float*)&bv[p][2])[c], ((const float*)&bv[p][3])[c]));
      }
    }
    __syncthreads();
    #pragma unroll
    for (int ks = 0; ks < 2; ++ks) {
      short8 af[4], bf[4];
      int kbyte = ks * 64 + (lane >> 4) * 16;
      #pragma unroll
      for (int mi = 0; mi < 4; ++mi)
        af[mi] = *(const short8*)(AsB + lds_off(wr * 64 + mi * 16 + (lane & 15), kbyte));
      #pragma unroll
      for (int ni = 0; ni < 4; ++ni)
        bf[ni] = *(const short8*)(BsB + lds_off(wc * 64 + ni * 16 + (lane & 15), kbyte));
      #pragma unroll
      for (int mi = 0; mi < 4; ++mi)
        #pragma unroll
        for (int ni = 0; ni < 4; ++ni)
          acc[mi][ni] = __builtin_amdgcn_mfma_f32_16x16x32_bf16(af[mi], bf[ni], acc[mi][ni], 0, 0, 0);
    }
  }

  const int colp = lane & 15;
  const int rgrp = lane >> 4;
  #pragma unroll
  for (int mi = 0; mi < 4; ++mi) {
    #pragma unroll
    for (int j = 0; j < 4; ++j) {
      int rowl = wr * 64 + mi * 16 + rgrp * 4 + j;
      float prob = pb[e * CAP + m0 + rowl];
      size_t arow = (size_t)(e * CAP + m0 + rowl) * INTER;
      #pragma unroll
      for (int ni = 0; ni < 4; ++ni) {
        float v = acc[mi][ni][j];
        float other = __shfl_xor(v, 1, 64);
        if ((lane & 1) == 0) {
          float gate = fminf(v, 7.0f);
          float up   = fminf(fmaxf(other, -7.0f), 7.0f);
          float glu  = gate / (1.0f + __expf(-1.702f * gate));
          float a    = glu * (up + 1.0f) * prob;
          int nh = n0 + wc * 64 + ni * 16 + colp;
          act[arow + (nh >> 1)] = __float2bfloat16(a);
        }
      }
    }
  }
}

__global__ __launch_bounds__(256) void k_gemm2(
    const __hip_bfloat16* __restrict__ act, const float* __restrict__ down,
    const int* __restrict__ counts, const int* __restrict__ tok,
    float* __restrict__ out)
{
  const int MT = CAP / 128;
  const int NT = DIM / 128;
  int bid = blockIdx.x;
  int e  = bid / (NT * MT);
  int rr = bid % (NT * MT);
  int nt = rr / MT;
  int mt = rr % MT;
  const int cnt = counts[e];
  const int m0 = mt * 128;
  if (m0 >= cnt) return;
  const int n0 = nt * 128;

  __shared__ unsigned char AsB[128 * 128];
  __shared__ unsigned char BsB[128 * 128];

  const int tid  = threadIdx.x;
  const int lane = tid & 63;
  const int wid  = tid >> 6;
  const int wr = wid >> 1, wc = wid & 1;

  const __hip_bfloat16* ab = act + (size_t)(e * CAP + m0) * INTER;
  const float* gb = down + (size_t)e * INTER * DIM + n0;

  int nb[2], kb[2];
  #pragma unroll
  for (int p = 0; p < 2; ++p) { int q = p * 256 + tid; nb[p] = q & 31; kb[p] = q >> 5; }
  int am[4], ak[4];
  #pragma unroll
  for (int p = 0; p < 4; ++p) { int q = p * 256 + tid; am[p] = q >> 3; ak[p] = q & 7; }

  f32x4 acc[4][4];
  #pragma unroll
  for (int i = 0; i < 4; ++i)
    #pragma unroll
    for (int j = 0; j < 4; ++j) acc[i][j] = (f32x4){0.f, 0.f, 0.f, 0.f};

  const int KT = INTER / 64;
  for (int kt = 0; kt < KT; ++kt) {
    int k0 = kt * 64;
    uint4 avv[4];
    #pragma unroll
    for (int p = 0; p < 4; ++p)
      avv[p] = *(const uint4*)(ab + (size_t)am[p] * INTER + k0 + ak[p] * 8);
    float4 bv[2][4];
    #pragma unroll
    for (int p = 0; p < 2; ++p) {
      const float* bp = gb + (size_t)(k0 + kb[p] * 4) * DIM + nb[p] * 4;
      #pragma unroll
      for (int j = 0; j < 4; ++j) bv[p][j] = *(const float4*)(bp + (size_t)j * DIM);
    }
    __syncthreads();
    #pragma unroll
    for (int p = 0; p < 4; ++p)
      *(uint4*)(AsB + lds_off(am[p], ak[p] * 16)) = avv[p];
    #pragma unroll
    for (int p = 0; p < 2; ++p) {
      #pragma unroll
      for (int c = 0; c < 4; ++c) {
        int n = nb[p] * 4 + c;
        *(uint2*)(BsB + lds_off(n, kb[p] * 8)) =
            make_uint2(pack_bf16(((const float*)&bv[p][0])[c], ((const float*)&bv[p][1])[c]),
                       pack_bf16(((const float*)&bv[p][2])[c], ((const float*)&bv[p][3])[c]));
      }
    }
    __syncthreads();
    #pragma unroll
    for (int ks = 0; ks < 2; ++ks) {
      short8 af[4], bf[4];
      int kbyte = ks * 64 + (lane >> 4) * 16;
      #pragma unroll
      for (int mi = 0; mi < 4; ++mi)
        af[mi] = *(const short8*)(AsB + lds_off(wr * 64 + mi * 16 + (lane & 15), kbyte));
      #pragma unroll
      for (int ni = 0; ni < 4; ++ni)
        bf[ni] = *(const short8*)(BsB + lds_off(wc * 64 + ni * 16 + (lane & 15), kbyte));
      #pragma unroll
      for (int mi = 0; mi < 4; ++mi)
        #pragma unroll
        for (int ni = 0; ni < 4; ++ni)
          acc[mi][ni] = __builtin_amdgcn_mfma_f32_16x16x32_bf16(af[mi], bf[ni], acc[mi][ni], 0, 0, 0);
    }
  }

  const int colp = lane & 15;
  const int rgrp = lane >> 4;
  #pragma unroll
  for (int mi = 0; mi < 4; ++mi) {
    #pragma unroll
    for (int j = 0; j < 4; ++j) {
      int rowl = wr * 64 + mi * 16 + rgrp * 4 + j;
      int t = tok[e * CAP + m0 + rowl];
      float* orow = out + (size_t)t * DIM + n0;
      #pragma unroll
      for (int ni = 0; ni < 4; ++ni)
        atomicAdd(orow + wc * 64 + ni * 16 + colp, acc[mi][ni][j]);
    }
  }
}

// ================= launch =================

extern "C" void kernel_launch(void* const* d_in, const int* in_sizes, int n_in,
                              void* d_out, int out_size, void* d_ws, size_t ws_size,
                              hipStream_t stream) {
  const float* x     = (const float*)d_in[0];
  const int*   tmask = (const int*)d_in[1];
  const float* w     = (const float*)d_in[2];
  const int*   idx   = (const int*)d_in[3];
  const float* gup   = (const float*)d_in[4];
  const float* down  = (const float*)d_in[5];
  float* out = (float*)d_out;

  char* ws = (char*)d_ws;
  const size_t off_tok   = 256;
  const size_t off_pb    = 256 + 131072;
  const size_t off_act   = 256 + 262144;                       // 262400
  const size_t act_bytes = (size_t)N_EXPERTS * CAP * INTER * 2; // 92,274,688
  const size_t off_xb    = off_act + act_bytes;
  const size_t xb_bytes  = (size_t)N_TOKENS * DIM * 2;          // 16,777,216
  const size_t off_gupT  = off_xb + xb_bytes;
  const size_t gupT_b    = (size_t)N_EXPERTS * TWO_INTER * DIM * 2; // 369,098,752
  const size_t off_downT = off_gupT + gupT_b;
  const size_t downT_b   = (size_t)N_EXPERTS * DIM * INTER * 2;     // 184,549,376
  const size_t need      = off_downT + downT_b;                      // ~663 MB

  int*   counts = (int*)ws;
  int*   tok    = (int*)(ws + off_tok);
  float* pbuf   = (float*)(ws + off_pb);
  __hip_bfloat16* act = (__hip_bfloat16*)(ws + off_act);

  hipMemsetAsync(ws, 0, off_act, stream);
  k_build<<<(T_ASSIGN + 255) / 256, 256, 0, stream>>>(tmask, w, idx, counts, tok, pbuf);
  hipMemsetAsync(d_out, 0, (size_t)N_TOKENS * DIM * sizeof(float), stream);

  if (ws_size >= need) {
    __hip_bfloat16* xb    = (__hip_bfloat16*)(ws + off_xb);
    __hip_bfloat16* gupT  = (__hip_bfloat16*)(ws + off_gupT);
    __hip_bfloat16* downT = (__hip_bfloat16*)(ws + off_downT);

    k_conv<<<2048, 256, 0, stream>>>(x, xb, (N_TOKENS * DIM) / 4);
    k_tconv<<<N_EXPERTS * (DIM / 64) * (TWO_INTER / 64), 256, 0, stream>>>(gup, gupT, DIM, TWO_INTER);
    k_tconv<<<N_EXPERTS * (INTER / 64) * (DIM / 64), 256, 0, stream>>>(down, downT, INTER, DIM);

    k_gemm1n<<<N_EXPERTS * (TWO_INTER / 128) * (CAP / 128), 256, 0, stream>>>(
        xb, gupT, counts, tok, pbuf, act);
    k_gemm2n<<<N_EXPERTS * (DIM / 128) * (CAP / 128), 256, 0, stream>>>(
        act, downT, counts, tok, out);
  } else {
    k_gemm1<<<N_EXPERTS * (TWO_INTER / 128) * (CAP / 128), 256, 0, stream>>>(
        x, gup, counts, tok, pbuf, act);
    k_gemm2<<<N_EXPERTS * (DIM / 128) * (CAP / 128), 256, 0, stream>>>(
        act, down, counts, tok, out);
  }
}